// Round 1
// baseline (860.215 us; speedup 1.0000x reference)
//
#include <hip/hip_runtime.h>
#include <math.h>

#define BB 16
#define HH 32
#define KVHH 8
#define GG 4
#define DD 128
#define SS 4096
#define PSTRIDE (GG * DD + 2 * GG)  // 520 floats: acc[4][128], m[4], l[4]
#define SCALE 0.08838834764831845f

// Split-S flash-decoding partials, two-phase (scores -> softmax -> PV).
// PG partials per (b,kvh); grid = B*KVH*(PG/8) blocks of 256 thr = 8 groups
// of 32 lanes. Group p handles a ctx-proportional chunk (dynamic balance).
// Phase 1: stream K, scores -> LDS (independent iters, batch-4 dbuf loads).
// Phase 2: exact max/sum per head, weights back to LDS (bank = lane).
// Phase 3: stream V, weighted accumulate (batch-4 dbuf loads).
template<int PG>
__global__ __launch_bounds__(256) void pa_split(
    const float* __restrict__ q,
    const float* __restrict__ kc,
    const float* __restrict__ vc,
    const int* __restrict__ slots,
    const int* __restrict__ positions,
    const int* __restrict__ ctxlen,
    float* __restrict__ part)
{
  constexpr int NSUB = PG / 8;
  constexpr int CH   = SS / PG;           // max chunk: 64 (PG=64) or 32 (PG=128)
  __shared__ float smem[8][CH][GG];       // scores, then weights; bank==lane

  const int blk  = blockIdx.x;
  const int sub  = blk % NSUB;
  const int bkv  = blk / NSUB;
  const int b    = bkv >> 3;              // KVH = 8
  const int kvh  = bkv & 7;
  const int tid  = threadIdx.x;
  const int lane = tid & 31;
  const int grp  = tid >> 5;
  const int p    = sub * 8 + grp;         // 0..PG-1
  const int ctx  = ctxlen[b];
  const int chunk = (ctx + PG - 1) / PG;  // ctx-proportional, <= CH
  const int s0   = p * chunk;
  int nvalid = ctx - s0;
  nvalid = nvalid < 0 ? 0 : (nvalid > chunk ? chunk : nvalid);

  const int d0 = lane * 4;
  // inv_freq for this lane's 4 d-values: 10000^(-j/64), j = d & 63
  float invf[4];
  #pragma unroll
  for (int i = 0; i < 4; ++i) {
    int j = (d0 + i) & 63;
    invf[i] = __expf(-0.14391156f * (float)j);   // ln(10000)/64
  }

  // ---- rope'd, pre-scaled query fragments for the 4 query heads ----
  const int pos_last = positions[b * SS + (ctx - 1)];
  float qsn[4], qcs[4];
  #pragma unroll
  for (int i = 0; i < 4; ++i)
    __sincosf((float)pos_last * invf[i], &qsn[i], &qcs[i]);
  float qr[GG][4];
  #pragma unroll
  for (int g = 0; g < GG; ++g) {
    const float4 x4 = *(const float4*)(q + ((size_t)b * HH + kvh * GG + g) * DD + d0);
    float x[4] = {x4.x, x4.y, x4.z, x4.w};
    #pragma unroll
    for (int i = 0; i < 4; ++i) {
      float px = __shfl_xor(x[i], 16, 32);       // partner element d ^ 64
      float r  = (lane < 16) ? -px : px;
      qr[g][i] = (x[i] * qcs[i] + r * qsn[i]) * SCALE;
    }
  }

  // preload slots/positions for the chunk (<= CH entries over 32 lanes)
  const int sbase = b * SS + s0;
  const int slotA = slots[sbase + lane];
  const int posA  = positions[sbase + lane];
  int slotB = 0, posB = 0;
  if constexpr (CH == 64) {
    slotB = slots[sbase + 32 + lane];
    posB  = positions[sbase + 32 + lane];
  }
  auto SLOT = [&](int it) {
    if constexpr (CH == 64)
      return (it < 32) ? __shfl(slotA, it, 32) : __shfl(slotB, it - 32, 32);
    else
      return __shfl(slotA, it, 32);
  };
  auto POS = [&](int it) {
    if constexpr (CH == 64)
      return (it < 32) ? __shfl(posA, it, 32) : __shfl(posB, it - 32, 32);
    else
      return __shfl(posA, it, 32);
  };

  // ================= phase 1: scores -> LDS =================
  auto LOADK = [&](float4 (&kb)[4], int base) {
    #pragma unroll
    for (int j = 0; j < 4; ++j) {
      int it = base + j;
      if (it < nvalid) {                 // group-uniform predicate
        int slot = SLOT(it);
        kb[j] = *(const float4*)(kc + ((size_t)slot * KVHH + kvh) * DD + d0);
      }
    }
  };
  auto COMPK = [&](float4 (&kb)[4], int base) {
    #pragma unroll
    for (int j = 0; j < 4; ++j) {
      int it = base + j;
      if (it < nvalid) {
        int pos = POS(it);
        float kx[4] = {kb[j].x, kb[j].y, kb[j].z, kb[j].w};
        float sc0 = 0.f, sc1 = 0.f, sc2 = 0.f, sc3 = 0.f;
        #pragma unroll
        for (int i = 0; i < 4; ++i) {
          float pk = __shfl_xor(kx[i], 16, 32);
          float r  = (lane < 16) ? -pk : pk;
          float sn, cs;
          __sincosf((float)pos * invf[i], &sn, &cs);
          float kr = kx[i] * cs + r * sn;
          sc0 += qr[0][i] * kr;
          sc1 += qr[1][i] * kr;
          sc2 += qr[2][i] * kr;
          sc3 += qr[3][i] * kr;
        }
        #pragma unroll
        for (int off = 16; off > 0; off >>= 1) {
          sc0 += __shfl_xor(sc0, off, 32);
          sc1 += __shfl_xor(sc1, off, 32);
          sc2 += __shfl_xor(sc2, off, 32);
          sc3 += __shfl_xor(sc3, off, 32);
        }
        if (lane < 4) {
          float v = lane == 0 ? sc0 : lane == 1 ? sc1 : lane == 2 ? sc2 : sc3;
          smem[grp][it][lane] = v;       // banks 4*it+lane : conflict-free
        }
      }
    }
  };

  float4 bufA[4], bufB[4];
  LOADK(bufA, 0);
  for (int base = 0; base < nvalid; base += 8) {
    LOADK(bufB, base + 4);
    COMPK(bufA, base);
    LOADK(bufA, base + 8);
    COMPK(bufB, base + 4);
  }

  // ================= phase 2: exact softmax over the chunk =================
  // lane -> (g = lane&3, t0 = lane>>2); addr it*4+g has bank == lane.
  const int g2 = lane & 3;
  const int t0 = lane >> 2;
  float mx = -1e30f;
  #pragma unroll
  for (int k = 0; k < CH / 8; ++k) {
    int it = t0 + 8 * k;
    if (it < nvalid) mx = fmaxf(mx, smem[grp][it][g2]);
  }
  mx = fmaxf(mx, __shfl_xor(mx, 4, 32));
  mx = fmaxf(mx, __shfl_xor(mx, 8, 32));
  mx = fmaxf(mx, __shfl_xor(mx, 16, 32));
  float ls = 0.f;
  #pragma unroll
  for (int k = 0; k < CH / 8; ++k) {
    int it = t0 + 8 * k;
    if (it < nvalid) {
      float w = __expf(smem[grp][it][g2] - mx);
      smem[grp][it][g2] = w;
      ls += w;
    }
  }
  ls += __shfl_xor(ls, 4, 32);
  ls += __shfl_xor(ls, 8, 32);
  ls += __shfl_xor(ls, 16, 32);
  // (nvalid==0 falls through with mx=-1e30, ls=0, acc=0 — combine handles it)

  // ================= phase 3: weighted V accumulate =================
  float acc[GG][4];
  #pragma unroll
  for (int g = 0; g < GG; ++g)
    #pragma unroll
    for (int i = 0; i < 4; ++i) acc[g][i] = 0.f;

  auto LOADV = [&](float4 (&vb)[4], int base) {
    #pragma unroll
    for (int j = 0; j < 4; ++j) {
      int it = base + j;
      if (it < nvalid) {
        int slot = SLOT(it);
        vb[j] = *(const float4*)(vc + ((size_t)slot * KVHH + kvh) * DD + d0);
      }
    }
  };
  auto COMPV = [&](float4 (&vb)[4], int base) {
    #pragma unroll
    for (int j = 0; j < 4; ++j) {
      int it = base + j;
      if (it < nvalid) {
        float w0 = smem[grp][it][0];   // same-address broadcast: free
        float w1 = smem[grp][it][1];
        float w2 = smem[grp][it][2];
        float w3 = smem[grp][it][3];
        float4 v4 = vb[j];
        acc[0][0] += w0 * v4.x; acc[0][1] += w0 * v4.y;
        acc[0][2] += w0 * v4.z; acc[0][3] += w0 * v4.w;
        acc[1][0] += w1 * v4.x; acc[1][1] += w1 * v4.y;
        acc[1][2] += w1 * v4.z; acc[1][3] += w1 * v4.w;
        acc[2][0] += w2 * v4.x; acc[2][1] += w2 * v4.y;
        acc[2][2] += w2 * v4.z; acc[2][3] += w2 * v4.w;
        acc[3][0] += w3 * v4.x; acc[3][1] += w3 * v4.y;
        acc[3][2] += w3 * v4.z; acc[3][3] += w3 * v4.w;
      }
    }
  };

  LOADV(bufA, 0);
  for (int base = 0; base < nvalid; base += 8) {
    LOADV(bufB, base + 4);
    COMPV(bufA, base);
    LOADV(bufA, base + 8);
    COMPV(bufB, base + 4);
  }

  // ================= write partial state =================
  float* pb = part + ((size_t)bkv * PG + p) * PSTRIDE;
  #pragma unroll
  for (int g = 0; g < GG; ++g)
    *(float4*)(pb + g * DD + d0) =
        make_float4(acc[g][0], acc[g][1], acc[g][2], acc[g][3]);
  if (lane < 4) {                        // lane == head g (t0 == 0 lanes)
    pb[GG * DD + lane]      = mx;
    pb[GG * DD + GG + lane] = ls;
  }
}

// Combine the PG partials per (b, h). grid = B*H, block = 128 (one d each).
template<int PG>
__global__ __launch_bounds__(128) void pa_combine(
    const float* __restrict__ part, float* __restrict__ out)
{
  const int bh  = blockIdx.x;      // 0..511
  const int b   = bh >> 5;
  const int h   = bh & 31;
  const int kvh = h >> 2;
  const int g   = h & 3;
  const int d   = threadIdx.x;

  const float* pbase = part + ((size_t)(b * KVHH + kvh)) * PG * PSTRIDE;
  float M = -1e30f, L = 0.f, o = 0.f;
  for (int p = 0; p < PG; ++p) {
    const float* pp = pbase + (size_t)p * PSTRIDE;
    float mp = pp[GG * DD + g];
    float lp = pp[GG * DD + GG + g];
    float a  = pp[g * DD + d];
    float Mn = fmaxf(M, mp);
    float e0 = __expf(M - Mn);
    float e1 = __expf(mp - Mn);
    o = o * e0 + a * e1;
    L = L * e0 + lp * e1;
    M = Mn;
  }
  out[((size_t)b * HH + h) * DD + d] = o / L;
}

extern "C" void kernel_launch(void* const* d_in, const int* in_sizes, int n_in,
                              void* d_out, int out_size, void* d_ws, size_t ws_size,
                              hipStream_t stream) {
  const float* q_p   = (const float*)d_in[0];
  const float* kc_p  = (const float*)d_in[1];
  const float* vc_p  = (const float*)d_in[2];
  const int*   slots = (const int*)d_in[3];
  const int*   poss  = (const int*)d_in[4];
  const int*   ctxl  = (const int*)d_in[5];
  float* part = (float*)d_ws;
  float* outp = (float*)d_out;

  const size_t need128 = (size_t)BB * KVHH * 128 * PSTRIDE * sizeof(float); // ~34 MB
  if (ws_size >= need128) {
    pa_split<128><<<BB * KVHH * 16, 256, 0, stream>>>(
        q_p, kc_p, vc_p, slots, poss, ctxl, part);
    pa_combine<128><<<BB * HH, 128, 0, stream>>>(part, outp);
  } else {
    pa_split<64><<<BB * KVHH * 8, 256, 0, stream>>>(
        q_p, kc_p, vc_p, slots, poss, ctxl, part);
    pa_combine<64><<<BB * HH, 128, 0, stream>>>(part, outp);
  }
}